// Round 9
// baseline (362.356 us; speedup 1.0000x reference)
//
#include <hip/hip_runtime.h>
#include <math.h>

#define N_NODES  50000
#define N_EDGES  800000
#define HID      64
#define OUT_DIM  12
#define N_LAYERS 4
#define N_GRAPHS 512

#define SCAN_CHUNK 512
#define N_CHUNKS   ((N_NODES + SCAN_CHUNK - 1) / SCAN_CHUNK)   // 98

typedef unsigned short u16;
typedef unsigned int   u32;
typedef __attribute__((ext_vector_type(8))) short bf16x8;   // 8 bf16 = 4 VGPRs
typedef __attribute__((ext_vector_type(4))) float f32x4;

__device__ __forceinline__ u32 f2bf(float f) {
    u32 u = __float_as_uint(f);
    return (u + 0x7FFFu + ((u >> 16) & 1u)) >> 16;   // RNE
}
__device__ __forceinline__ float bf2f(u32 h) {
    return __uint_as_float(h << 16);
}
__device__ __forceinline__ float bf2f_hi(u32 h) {
    return __uint_as_float(h & 0xffff0000u);
}

// ---------------------------------------------------------------------------
// Weight prep (once): wt[m][n][k] bf16, m = layer*4 + {0:q,1:v,2:k,3:s}
// ---------------------------------------------------------------------------
__global__ __launch_bounds__(256) void wprep_kernel(
    const float* __restrict__ Wq, const float* __restrict__ Wv,
    const float* __restrict__ Wk, const float* __restrict__ Ws,
    u16* __restrict__ wt)
{
    int m = blockIdx.x;          // 0..15
    int lyr = m >> 2, j = m & 3;
    const float* src;
    switch (j) { case 0: src = Wq; break; case 1: src = Wv; break;
                 case 2: src = Wk; break; default: src = Ws; }
    src += (size_t)lyr * HID * HID;
    int t  = threadIdx.x;
    int n  = t >> 2;             // output row (col of W)
    int k0 = (t & 3) * 16;       // 16 k per thread
    u32 buf[8];
    #pragma unroll
    for (int i = 0; i < 16; i += 2) {
        float f0 = src[(k0 + i) * HID + n];
        float f1 = src[(k0 + i + 1) * HID + n];
        buf[i / 2] = f2bf(f0) | (f2bf(f1) << 16);
    }
    u32* dst = (u32*)(wt + (size_t)m * 4096 + n * 64 + k0);
    *(uint4*)(dst)     = make_uint4(buf[0], buf[1], buf[2], buf[3]);
    *(uint4*)(dst + 4) = make_uint4(buf[4], buf[5], buf[6], buf[7]);
}

// ---------------------------------------------------------------------------
// Layer-0 input convert: f32 -> packed bf16
// ---------------------------------------------------------------------------
__global__ __launch_bounds__(256) void cvt_kernel(
    const float* __restrict__ x, u32* __restrict__ xbf)
{
    int i = blockIdx.x * 256 + threadIdx.x;          // 8 floats per thread
    if (i >= N_NODES * HID / 8) return;
    float4 a = ((const float4*)x)[2 * i];
    float4 b = ((const float4*)x)[2 * i + 1];
    ((uint4*)xbf)[i] = make_uint4(
        f2bf(a.x) | (f2bf(a.y) << 16), f2bf(a.z) | (f2bf(a.w) << 16),
        f2bf(b.x) | (f2bf(b.y) << 16), f2bf(b.z) | (f2bf(b.w) << 16));
}

// ---------------------------------------------------------------------------
// MFMA GEMM: blockIdx.y=0 -> (Wq,Wv) -> interleaved bf16 qv
//            blockIdx.y=1 -> (Wk,Ws) -> packed bf16 kbf + f32 os
// 64 nodes per block (4 waves x 16), mfma_f32_16x16x32_bf16, no LDS.
// C/D: col=lane&15, row=(lane>>4)*4+reg.
// ---------------------------------------------------------------------------
__global__ __launch_bounds__(256) void gemm_mfma_kernel(
    const u16* __restrict__ xbf, const u16* __restrict__ wt, int layer,
    const float* __restrict__ bq, const float* __restrict__ bv,
    const float* __restrict__ bk, const float* __restrict__ bs,
    u32* __restrict__ qv, u32* __restrict__ kbf, float* __restrict__ os)
{
    const int t = threadIdx.x;
    const int w = t >> 6;
    const int l = t & 63;
    const int row16 = l & 15;
    const int kgrp  = l >> 4;
    const int gbase = blockIdx.x * 64;

    const u16 *wA, *wB; const float *bA, *bB;
    if (blockIdx.y == 0) { wA = wt + (size_t)(layer * 4 + 0) * 4096; bA = bq;
                           wB = wt + (size_t)(layer * 4 + 1) * 4096; bB = bv; }
    else                 { wA = wt + (size_t)(layer * 4 + 2) * 4096; bA = bk;
                           wB = wt + (size_t)(layer * 4 + 3) * 4096; bB = bs; }

    int nodeA = gbase + w * 16 + row16;
    int nodeAc = nodeA < N_NODES ? nodeA : N_NODES - 1;
    bf16x8 a0 = *(const bf16x8*)(xbf + (size_t)nodeAc * 64 + kgrp * 8);
    bf16x8 a1 = *(const bf16x8*)(xbf + (size_t)nodeAc * 64 + 32 + kgrp * 8);

    f32x4 acc[2][4];
    #pragma unroll
    for (int nt = 0; nt < 4; ++nt) {
        float fa = bA[nt * 16 + row16];
        float fb = bB[nt * 16 + row16];
        acc[0][nt] = (f32x4){fa, fa, fa, fa};
        acc[1][nt] = (f32x4){fb, fb, fb, fb};
    }

    #pragma unroll
    for (int nt = 0; nt < 4; ++nt) {
        const u16* pa = wA + (nt * 16 + row16) * 64 + kgrp * 8;
        const u16* pb = wB + (nt * 16 + row16) * 64 + kgrp * 8;
        bf16x8 ba0 = *(const bf16x8*)(pa);
        bf16x8 ba1 = *(const bf16x8*)(pa + 32);
        bf16x8 bb0 = *(const bf16x8*)(pb);
        bf16x8 bb1 = *(const bf16x8*)(pb + 32);
        acc[0][nt] = __builtin_amdgcn_mfma_f32_16x16x32_bf16(a0, ba0, acc[0][nt], 0, 0, 0);
        acc[0][nt] = __builtin_amdgcn_mfma_f32_16x16x32_bf16(a1, ba1, acc[0][nt], 0, 0, 0);
        acc[1][nt] = __builtin_amdgcn_mfma_f32_16x16x32_bf16(a0, bb0, acc[1][nt], 0, 0, 0);
        acc[1][nt] = __builtin_amdgcn_mfma_f32_16x16x32_bf16(a1, bb1, acc[1][nt], 0, 0, 0);
    }

    if (blockIdx.y == 0) {
        // pack adjacent cols (2c,2c+1) into u32 bf16 pairs; interleave q,v
        #pragma unroll
        for (int nt = 0; nt < 4; ++nt) {
            #pragma unroll
            for (int r = 0; r < 4; ++r) {
                float qe = acc[0][nt][r];
                float qo = __shfl_xor(qe, 1);
                float ve = acc[1][nt][r];
                float vo = __shfl_xor(ve, 1);
                if (!(l & 1)) {
                    int gn = gbase + w * 16 + kgrp * 4 + r;
                    if (gn < N_NODES) {
                        u32 qp = f2bf(qe) | (f2bf(qo) << 16);
                        u32 vp = f2bf(ve) | (f2bf(vo) << 16);
                        *(uint2*)(qv + (size_t)gn * 64 + nt * 16 + row16) = make_uint2(qp, vp);
                    }
                }
            }
        }
    } else {
        // k packed bf16 pairs; s full f32
        #pragma unroll
        for (int nt = 0; nt < 4; ++nt) {
            #pragma unroll
            for (int r = 0; r < 4; ++r) {
                float ke = acc[0][nt][r];
                float ko = __shfl_xor(ke, 1);
                int gn = gbase + w * 16 + kgrp * 4 + r;
                if (gn < N_NODES) {
                    int col = nt * 16 + row16;
                    os[(size_t)gn * 64 + col] = acc[1][nt][r];
                    if (!(l & 1))
                        kbf[(size_t)gn * 32 + (col >> 1)] = f2bf(ke) | (f2bf(ko) << 16);
                }
            }
        }
    }
}

// ---------------------------------------------------------------------------
// CSR build: histogram of dst (rank = arrival order), scan, rank-scatter.
// csr_off stores PRE-SCALED byte offsets (src*256) into the qv buffer.
// ---------------------------------------------------------------------------
__global__ __launch_bounds__(256) void hist_kernel(
    const int* __restrict__ ei, int* __restrict__ deg, int* __restrict__ rank)
{
    int e0 = (blockIdx.x * 256 + threadIdx.x) * 4;
    #pragma unroll
    for (int i = 0; i < 4; ++i) {
        int e = e0 + i;
        if (e < N_EDGES) rank[e] = atomicAdd(&deg[ei[N_EDGES + e]], 1);
    }
}

__global__ __launch_bounds__(SCAN_CHUNK) void scan1_kernel(
    const int* __restrict__ deg, int* __restrict__ base, int* __restrict__ blocksum)
{
    __shared__ int s[SCAN_CHUNK];
    int t = threadIdx.x;
    int i = blockIdx.x * SCAN_CHUNK + t;
    int v = (i < N_NODES) ? deg[i] : 0;
    s[t] = v;
    __syncthreads();
    for (int off = 1; off < SCAN_CHUNK; off <<= 1) {
        int u = (t >= off) ? s[t - off] : 0;
        __syncthreads();
        s[t] += u;
        __syncthreads();
    }
    if (i < N_NODES) base[i] = s[t] - v;              // exclusive
    if (t == SCAN_CHUNK - 1) blocksum[blockIdx.x] = s[t];
}

__global__ __launch_bounds__(128) void scan2_kernel(
    const int* __restrict__ blocksum, int* __restrict__ blockoff)
{
    __shared__ int s[128];
    int t = threadIdx.x;
    int v = (t < N_CHUNKS) ? blocksum[t] : 0;
    s[t] = v;
    __syncthreads();
    for (int off = 1; off < 128; off <<= 1) {
        int u = (t >= off) ? s[t - off] : 0;
        __syncthreads();
        s[t] += u;
        __syncthreads();
    }
    if (t < N_CHUNKS) blockoff[t] = s[t] - v;         // exclusive
}

__global__ __launch_bounds__(SCAN_CHUNK) void scan3_kernel(
    int* __restrict__ base, const int* __restrict__ blockoff)
{
    int i = blockIdx.x * SCAN_CHUNK + threadIdx.x;
    if (i < N_NODES) base[i] += blockoff[blockIdx.x];
    if (i == 0) base[N_NODES] = N_EDGES;
}

__global__ __launch_bounds__(256) void scatter_kernel(
    const int* __restrict__ ei, const int* __restrict__ base,
    const int* __restrict__ rank, u32* __restrict__ csr_off)
{
    int e0 = (blockIdx.x * 256 + threadIdx.x) * 4;
    #pragma unroll
    for (int i = 0; i < 4; ++i) {
        int e = e0 + i;
        if (e < N_EDGES)
            csr_off[base[ei[N_EDGES + e]] + rank[e]] = ((u32)ei[e]) << 8;
    }
}

// ---------------------------------------------------------------------------
// Gather aggregation + skip + GELU. One wave per node.
// Lane = (equad, c4): equad = lane>>4 strides edges by 4; c4 = lane&15 covers
// channels 4*c4..4*c4+3 via ONE uint4 load (wave instr = 4 full 256B rows).
// csr_off holds src*256 byte offsets. k packed bf16; out packed bf16.
// ---------------------------------------------------------------------------
__global__ __launch_bounds__(256) void agg_gelu_kernel(
    const int* __restrict__ base, const u32* __restrict__ csr_off,
    const u32* __restrict__ kbf, const u32* __restrict__ qv,
    const float* __restrict__ skip, u32* __restrict__ outxbf)
{
    int node = blockIdx.x * 4 + (threadIdx.x >> 6);
    if (node >= N_NODES) return;
    int lane  = threadIdx.x & 63;
    int equad = lane >> 4;            // 0..3
    int c4    = lane & 15;            // channel quad: 4*c4 .. 4*c4+3

    uint2 kp = *(const uint2*)(kbf + (size_t)node * 32 + 2 * c4);
    float kd0 = bf2f(kp.x & 0xffffu), kd1 = bf2f_hi(kp.x);
    float kd2 = bf2f(kp.y & 0xffffu), kd3 = bf2f_hi(kp.y);

    float acc0 = 0.f, acc1 = 0.f, acc2 = 0.f, acc3 = 0.f;
    int p0 = base[node];
    int p1 = base[node + 1];
    const char* qvb = (const char*)qv + c4 * 16;   // per-lane column base

    for (int p = p0 + equad; p < p1; p += 4) {
        u32 off = csr_off[p];                       // src*256
        uint4 e = *(const uint4*)(qvb + off);       // (q01, v01, q23, v23)
        float g;
        g = 1.f / (1.f + __expf(-(kd0 + bf2f(e.x & 0xffffu)))); acc0 = fmaf(g, bf2f(e.y & 0xffffu), acc0);
        g = 1.f / (1.f + __expf(-(kd1 + bf2f_hi(e.x))));        acc1 = fmaf(g, bf2f_hi(e.y),        acc1);
        g = 1.f / (1.f + __expf(-(kd2 + bf2f(e.z & 0xffffu)))); acc2 = fmaf(g, bf2f(e.w & 0xffffu), acc2);
        g = 1.f / (1.f + __expf(-(kd3 + bf2f_hi(e.z))));        acc3 = fmaf(g, bf2f_hi(e.w),        acc3);
    }

    // reduce across the 4 edge-quads (lanes with equal c4, stride 16)
    acc0 += __shfl_xor(acc0, 16); acc1 += __shfl_xor(acc1, 16);
    acc2 += __shfl_xor(acc2, 16); acc3 += __shfl_xor(acc3, 16);
    acc0 += __shfl_xor(acc0, 32); acc1 += __shfl_xor(acc1, 32);
    acc2 += __shfl_xor(acc2, 32); acc3 += __shfl_xor(acc3, 32);

    if (equad == 0) {
        float4 sk = *(const float4*)(skip + (size_t)node * HID + 4 * c4);
        float x0 = acc0 + sk.x, x1 = acc1 + sk.y;
        float x2 = acc2 + sk.z, x3 = acc3 + sk.w;
        float g0 = 0.5f * x0 * (1.f + erff(x0 * 0.70710678118f));
        float g1 = 0.5f * x1 * (1.f + erff(x1 * 0.70710678118f));
        float g2 = 0.5f * x2 * (1.f + erff(x2 * 0.70710678118f));
        float g3 = 0.5f * x3 * (1.f + erff(x3 * 0.70710678118f));
        *(uint2*)(outxbf + (size_t)node * 32 + 2 * c4) =
            make_uint2(f2bf(g0) | (f2bf(g1) << 16), f2bf(g2) | (f2bf(g3) << 16));
    }
}

// ---------------------------------------------------------------------------
// Graph boundaries from sorted batch
// ---------------------------------------------------------------------------
__global__ __launch_bounds__(256) void bounds_kernel(
    const int* __restrict__ batch, int* __restrict__ start)
{
    int n = blockIdx.x * 256 + threadIdx.x;
    if (n >= N_NODES) return;
    int b  = batch[n];
    int bp = (n == 0) ? -1 : batch[n - 1];
    for (int g = bp + 1; g <= b; ++g) start[g] = n;
    if (n == N_NODES - 1) {
        for (int g = b + 1; g <= N_GRAPHS; ++g) start[g] = N_NODES;
    }
}

// ---------------------------------------------------------------------------
// Mean pool from packed bf16 x: 8 node-streams x 32 chanpairs per block
// ---------------------------------------------------------------------------
__global__ __launch_bounds__(256) void pool2_kernel(
    const u32* __restrict__ xbf, const int* __restrict__ start,
    float* __restrict__ pooled)
{
    int g   = blockIdx.x;
    int t   = threadIdx.x;
    int nid = t >> 5;             // 0..7
    int c   = t & 31;
    int s0 = start[g];
    int s1 = start[g + 1];
    float a0 = 0.f, a1 = 0.f;
    for (int n = s0 + nid; n < s1; n += 8) {
        u32 p = xbf[(size_t)n * 32 + c];
        a0 += bf2f(p & 0xffffu);
        a1 += bf2f(p >> 16);
    }
    __shared__ float red0[8][32], red1[8][32];
    red0[nid][c] = a0; red1[nid][c] = a1;
    __syncthreads();
    if (nid == 0) {
        float t0 = 0.f, t1 = 0.f;
        #pragma unroll
        for (int i = 0; i < 8; ++i) { t0 += red0[i][c]; t1 += red1[i][c]; }
        float cnt = fmaxf((float)(s1 - s0), 1.f);
        *(float2*)(pooled + (size_t)g * HID + 2 * c) = make_float2(t0 / cnt, t1 / cnt);
    }
}

// ---------------------------------------------------------------------------
// Head: h = relu(pooled@W1+b1); out = h@W2+b2. One block per graph.
// ---------------------------------------------------------------------------
__global__ __launch_bounds__(64) void head_kernel(
    const float* __restrict__ pooled,
    const float* __restrict__ w1, const float* __restrict__ b1,
    const float* __restrict__ w2, const float* __restrict__ b2,
    float* __restrict__ out)
{
    int g = blockIdx.x;
    int t = threadIdx.x;
    __shared__ float p[64];
    __shared__ float h[64];
    p[t] = pooled[(size_t)g * HID + t];
    __syncthreads();
    float acc = b1[t];
    #pragma unroll 8
    for (int k = 0; k < HID; ++k) acc = fmaf(p[k], w1[k * HID + t], acc);
    h[t] = fmaxf(acc, 0.f);
    __syncthreads();
    if (t < OUT_DIM) {
        float a2 = b2[t];
        #pragma unroll 8
        for (int k = 0; k < HID; ++k) a2 = fmaf(h[k], w2[k * OUT_DIM + t], a2);
        out[(size_t)g * OUT_DIM + t] = a2;
    }
}

// ---------------------------------------------------------------------------
extern "C" void kernel_launch(void* const* d_in, const int* in_sizes, int n_in,
                              void* d_out, int out_size, void* d_ws, size_t ws_size,
                              hipStream_t stream)
{
    const float* x     = (const float*)d_in[0];
    const int*   ei    = (const int*)d_in[1];
    const int*   batch = (const int*)d_in[2];
    const float* Wk = (const float*)d_in[4];
    const float* bk = (const float*)d_in[5];
    const float* Wq = (const float*)d_in[6];
    const float* bq = (const float*)d_in[7];
    const float* Wv = (const float*)d_in[8];
    const float* bv = (const float*)d_in[9];
    const float* Ws = (const float*)d_in[10];
    const float* bs = (const float*)d_in[11];
    const float* w1 = (const float*)d_in[12];
    const float* b1 = (const float*)d_in[13];
    const float* w2 = (const float*)d_in[14];
    const float* b2 = (const float*)d_in[15];
    float* out = (float*)d_out;

    char* wsb = (char*)d_ws;
    const size_t NF = (size_t)N_NODES * HID;
    u32*   xbf    = (u32*)wsb;                      wsb += NF * 2;   // packed bf16 x
    u32*   bufK   = (u32*)wsb;                      wsb += NF * 2;   // packed bf16 k
    float* bufS   = (float*)wsb;                    wsb += NF * 4;   // skip f32 (also CSR scratch)
    u32*   bufQV  = (u32*)wsb;                      wsb += NF * 4;   // interleaved bf16 q,v
    u16*   wt     = (u16*)wsb;                      wsb += (size_t)16 * 4096 * 2;
    float* pooled = (float*)wsb;                    wsb += (size_t)N_GRAPHS * HID * 4;
    int*   baseI  = (int*)wsb;                      wsb += (N_NODES + 1) * 4;
    u32*   csr_off= (u32*)wsb;                      wsb += (size_t)N_EDGES * 4;
    int*   startI = (int*)wsb;                      wsb += (N_GRAPHS + 1) * 4;
    // transient CSR scratch inside bufS (first written by gemm layer 0, which
    // runs after the CSR build in stream order)
    int* deg      = (int*)bufS;
    int* rank     = deg + N_NODES;
    int* blocksum = rank + N_EDGES;
    int* blockoff = blocksum + 128;

    const int gemm_gx = (N_NODES + 63) / 64;            // 782
    const int e4g     = (N_EDGES / 4 + 255) / 256;      // 782
    const int agg_gx  = (N_NODES + 3) / 4;              // 12500
    const int nd_g    = (N_NODES + 255) / 256;          // 196
    const int cvt_g   = ((int)(NF / 8) + 255) / 256;    // 1563

    // ---- one-time prep: weights, x->bf16, CSR, bounds ----
    hipMemsetAsync(deg, 0, (size_t)N_NODES * sizeof(int), stream);
    wprep_kernel<<<16, 256, 0, stream>>>(Wq, Wv, Wk, Ws, wt);
    cvt_kernel<<<cvt_g, 256, 0, stream>>>(x, xbf);
    hist_kernel<<<e4g, 256, 0, stream>>>(ei, deg, rank);
    scan1_kernel<<<N_CHUNKS, SCAN_CHUNK, 0, stream>>>(deg, baseI, blocksum);
    scan2_kernel<<<1, 128, 0, stream>>>(blocksum, blockoff);
    scan3_kernel<<<N_CHUNKS, SCAN_CHUNK, 0, stream>>>(baseI, blockoff);
    scatter_kernel<<<e4g, 256, 0, stream>>>(ei, baseI, rank, csr_off);
    bounds_kernel<<<nd_g, 256, 0, stream>>>(batch, startI);

    // ---- layers ----
    for (int l = 0; l < N_LAYERS; ++l) {
        gemm_mfma_kernel<<<dim3(gemm_gx, 2), 256, 0, stream>>>(
            (const u16*)xbf, wt, l,
            bq + (size_t)l * HID, bv + (size_t)l * HID,
            bk + (size_t)l * HID, bs + (size_t)l * HID,
            bufQV, bufK, bufS);
        agg_gelu_kernel<<<agg_gx, 256, 0, stream>>>(
            baseI, csr_off, bufK, bufQV, bufS, xbf);
    }

    // ---- pool + head ----
    pool2_kernel<<<N_GRAPHS, 256, 0, stream>>>(xbf, startI, pooled);
    head_kernel<<<N_GRAPHS, 64, 0, stream>>>(pooled, w1, b1, w2, b2, out);
}